// Round 6
// baseline (685.576 us; speedup 1.0000x reference)
//
#include <hip/hip_runtime.h>
#include <hip/hip_bf16.h>
#include <math.h>

// B=2,H=12 -> 24 heads, S=2048, D=64, fp32 in; out = ctx[24,2048,64] ++ attn[24,2048,2048].
//
// Round 8: round-7 structure + issue-order fixes (all value-preserving, bit-identical).
//  Diagnosis (round-7 counters): FETCH collapsed to 28MB (L2 fix confirmed) but 62% of
//  cycles still stalled. Two ordering bugs:
//   (a) vmcnt FIFO: attn NT stores issue BEFORE next-step K loads -> every QK wait also
//       waits store retirement (~500-900cy). Fix: per iteration, issue V[step] and
//       K[step+1] loads BEFORE the stores; stores get a full iteration of slack.
//   (b) VGPR=68 proves K loads go in ~4 serialized batches (4 L2 round-trips/step).
//       Fix: explicit QK_LOAD of all 16 fragments into a named array (one exposure),
//       then QK_MFMA. VGPR ~130-155 <= 170 keeps 3 waves/SIMD (grid-capped occupancy).
//   (c) DOT_EPS 0.02 -> 0.01 (still 1.7x the 5.8e-3 proven split-error bound) halves the
//       divergent exact_dot fallbacks on the e-chain critical path.

#define S_LEN 2048
#define DK    64
#define MQ    64
#define NSTEP (S_LEN / 64)      // 32 k-slabs of 64
#define NQB   (S_LEN / MQ)      // 32
#define DOT_EPS 0.01f

typedef __attribute__((ext_vector_type(8))) short bf16x8;
typedef __attribute__((ext_vector_type(4))) float f32x4;

__device__ inline short f2bf(float x) {
  __hip_bfloat16 b = __float2bfloat16(x);
  return *reinterpret_cast<short*>(&b);
}
__device__ inline float bf2f(short s) {
  __hip_bfloat16 b = *reinterpret_cast<__hip_bfloat16*>(&s);
  return __bfloat162float(b);
}

// exact round-1 score chain: sequential fmaf over d=0..63 (bit-identical to baseline)
__device__ float exact_dot(const float* Qr, const float* __restrict__ Kr) {
  float acc = 0.f;
  #pragma unroll
  for (int d4 = 0; d4 < 16; ++d4) {
    float4 a = ((const float4*)Qr)[d4];
    float4 b = ((const float4*)Kr)[d4];
    acc = fmaf(a.x, b.x, acc);
    acc = fmaf(a.y, b.y, acc);
    acc = fmaf(a.z, b.z, acc);
    acc = fmaf(a.w, b.w, acc);
  }
  return acc;
}

// ---------------- prep kernel: build bf16 planes in ws ----------------
// QW: per head [q][plane2][64]                       (plain)
// KW: per head [kt16:128][row16][plane2][blk8^ (row&7)][8]
// VW: per head [slab:32][d64][blk8 ^ (d&7)][8]       (V transposed: Vt[d][k])
__global__ __launch_bounds__(256) void prep_kernel(
    const float* __restrict__ Q, const float* __restrict__ K, const float* __restrict__ V,
    short* __restrict__ qw, short* __restrict__ kw, short* __restrict__ vw, int secblocks) {
  const int bid = blockIdx.x, tid = threadIdx.x;
  if (bid < secblocks) {               // ---- Q section ----
    int flat = bid * 256 + tid;        // (head, q, b) over heads*2048*8
    int head = flat >> 14;
    int rem = flat & 16383;
    int q = rem >> 3, b = rem & 7;
    const float* src = Q + (size_t)(head * S_LEN + q) * DK + b * 8;
    bf16x8 hv, mv;
    #pragma unroll
    for (int i = 0; i < 8; ++i) {
      float x = src[i];
      short h = f2bf(x);
      short m = f2bf(x - bf2f(h));
      hv[i] = h; mv[i] = m;
    }
    short* dst = qw + (size_t)(head * S_LEN + q) * 128;
    *(bf16x8*)(dst + 0 * 64 + b * 8) = hv;
    *(bf16x8*)(dst + 1 * 64 + b * 8) = mv;
  } else if (bid < 2 * secblocks) {    // ---- K section ----
    int flat = (bid - secblocks) * 256 + tid;   // (head, kt, row, b)
    int head = flat >> 14;
    int rem = flat & 16383;
    int kt = rem >> 7;
    int row = (rem >> 3) & 15, b = rem & 7;
    const float* src = K + (size_t)(head * S_LEN + kt * 16 + row) * DK + b * 8;
    bf16x8 hv, mv;
    #pragma unroll
    for (int i = 0; i < 8; ++i) {
      float x = src[i];
      short h = f2bf(x);
      short m = f2bf(x - bf2f(h));
      hv[i] = h; mv[i] = m;
    }
    int bs = b ^ (row & 7);
    short* dst = kw + ((size_t)(head * 128 + kt) * 16 + row) * 128;
    *(bf16x8*)(dst + 0 * 64 + bs * 8) = hv;
    *(bf16x8*)(dst + 1 * 64 + bs * 8) = mv;
  } else {                             // ---- V section (transpose) ----
    int wid = (bid - 2 * secblocks) * 4 + (tid >> 6);  // (head, slab, b) over heads*32*8
    int lane = tid & 63;               // = d
    int head = wid >> 8;
    int rem = wid & 255;
    int slab = rem >> 3, b = rem & 7;
    bf16x8 vv;
    #pragma unroll
    for (int j = 0; j < 8; ++j)
      vv[j] = f2bf(V[(size_t)(head * S_LEN + slab * 64 + b * 8 + j) * DK + lane]);
    int bs = b ^ (lane & 7);
    *(bf16x8*)(vw + ((size_t)(head * 32 + slab) * 64 + lane) * 64 + bs * 8) = vv;
  }
}

// ---------------- main kernel: zero-barrier, per-wave independent, XCD-clustered --------
__global__ __launch_bounds__(256, 3) void sdpa_mfma(
    const float* __restrict__ Q, const float* __restrict__ K,
    const short* __restrict__ qw, const short* __restrict__ kw, const short* __restrict__ vw,
    float* __restrict__ ctx_out, float* __restrict__ attn_out) {
  __shared__ short es[4][1024];     // per-wave [q16][k64] bf16, 16B-block swizzle ^ (q&7)
  __shared__ float att[4][1024];    // per-wave 4KB f32 attn bounce: [row16][blk16 ^ row][4]
  __shared__ float Qs[64][64];      // block's 64 q-rows fp32 (for exact_dot), 16KB

  // XCD-aware decode: b = (head%8) + 8*(qb + 32*(head/8)); XCD = b%8 = head%8 ->
  // all 32 q-blocks of a head share one XCD's L2 (working set < 4MB).
  const int b = blockIdx.x;
  const int inner = b >> 3;
  const int qb = inner & (NQB - 1);
  const int head = (b & 7) + 8 * (inner >> 5);
  const int q0 = qb * MQ;
  const int tid = threadIdx.x;
  const int w = tid >> 6;
  const int lane = tid & 63;
  const int l15 = lane & 15;
  const int quad = lane >> 4;
  const int qrow = q0 + 16 * w + l15;    // this thread's q row (fixed for whole kernel)

  const short* QW = qw + (size_t)head * (S_LEN * 128);
  const short* KW = kw + (size_t)head * (128 * 16 * 128);
  const short* VW = vw + (size_t)head * (32 * 4096);
  const float* Qg = Q + (size_t)head * S_LEN * DK;
  const float* Kg = K + (size_t)head * S_LEN * DK;

  const f32x4 zf = {0.f, 0.f, 0.f, 0.f};

  // stage this block's Q fp32 rows into LDS (verbatim copy -> exact_dot bit-identical)
  #pragma unroll
  for (int i = 0; i < 4; ++i) {
    int idx = tid + 256 * i;            // float4 index over [64][16]
    ((float4*)Qs)[idx] = ((const float4*)(Qg + (size_t)q0 * DK))[idx];
  }

  // Q B-operand fragments for THIS wave's q-tile only. B[k=d][n=q]: n=l15 -> q = qrow;
  // k = c*32 + quad*8 + j.
  bf16x8 qf[2][2];   // [plane][chunk]
  #pragma unroll
  for (int p = 0; p < 2; ++p)
    #pragma unroll
    for (int c = 0; c < 2; ++c)
      qf[p][c] = *(const bf16x8*)(QW + (size_t)qrow * 128 + p * 64 + (c * 4 + quad) * 8);

  __syncthreads();   // Qs staged (only barrier in the kernel)

  // ---- batched K-fragment load: all 16 loads issued back-to-back (one L2 exposure) ----
  #define QK_LOAD(kk, sb)                                                                      \
    {                                                                                          \
      _Pragma("unroll")                                                                        \
      for (int kt = 0; kt < 4; ++kt)                                                           \
        _Pragma("unroll")                                                                      \
        for (int p = 0; p < 2; ++p)                                                            \
          _Pragma("unroll")                                                                    \
          for (int c = 0; c < 2; ++c)                                                          \
            kk[kt][p][c] = *(const bf16x8*)((sb) + ((size_t)kt * 16 + l15) * 128 + p * 64 +    \
                                            (((c * 4 + quad) ^ (l15 & 7)) * 8));               \
    }

  // ---- MFMA chain: same per-acc order as all passing rounds -> bit-identical dots ----
  #define QK_MFMA(acc, kk)                                                                     \
    {                                                                                          \
      _Pragma("unroll")                                                                        \
      for (int kt = 0; kt < 4; ++kt)                                                           \
        _Pragma("unroll")                                                                      \
        for (int c = 0; c < 2; ++c) {                                                          \
          acc[kt] = __builtin_amdgcn_mfma_f32_16x16x32_bf16(kk[kt][0][c], qf[0][c], acc[kt], 0, 0, 0); \
          acc[kt] = __builtin_amdgcn_mfma_f32_16x16x32_bf16(kk[kt][1][c], qf[0][c], acc[kt], 0, 0, 0); \
          acc[kt] = __builtin_amdgcn_mfma_f32_16x16x32_bf16(kk[kt][0][c], qf[1][c], acc[kt], 0, 0, 0); \
        }                                                                                      \
    }

  bf16x8 kk[4][2][2];   // 64 VGPR K-fragment buffer (reused as next-step prefetch in pass B)

  // ================= pass A: Z (no barriers) =================
  float zsum = 0.f;
  for (int step = 0; step < NSTEP; ++step) {
    QK_LOAD(kk, KW + (size_t)step * 8192);
    f32x4 acc[4] = {zf, zf, zf, zf};
    QK_MFMA(acc, kk);
    #pragma unroll
    for (int kt = 0; kt < 4; ++kt)
      #pragma unroll
      for (int r = 0; r < 4; ++r) {
        float d = acc[kt][r];
        zsum += (d < 0.f) ? __expf(d * 0.125f) : 0.f;
      }
  }
  // quads hold disjoint k for the same q=l15 -> butterfly over lane bits 4,5
  zsum += __shfl_xor(zsum, 16);
  zsum += __shfl_xor(zsum, 32);
  const float zinv = 1.f / (zsum + 1e-8f);

  // ================= pass B: attn + PV (no barriers) =================
  f32x4 ctxa[4] = {zf, zf, zf, zf};   // ctx^T: [dt]; row d=dt*16+quad*4+r, col q=qrow
  short* esw = &es[w][0];             // this wave's private e tile (bf16)
  float* aw = &att[w][0];             // this wave's private attn bounce tile (f32)
  const float* Qlds = &Qs[16 * w + l15][0];   // this thread's q-row in LDS

  QK_LOAD(kk, KW);                    // prologue: K[0]

  for (int step = 0; step < NSTEP; ++step) {
    f32x4 acc[4] = {zf, zf, zf, zf};
    QK_MFMA(acc, kk);                 // wait leaves younger stores outstanding (vmcnt>=4)

    #pragma unroll
    for (int kt = 0; kt < 4; ++kt) {
      const int kbase = step * 64 + kt * 16 + quad * 4;
      float e4[4];
      #pragma unroll
      for (int r = 0; r < 4; ++r) {
        float d = acc[kt][r];
        if (fabsf(d) < DOT_EPS) {   // rare (~0.1%): exact sign via round-1 chain
          d = exact_dot(Qlds, Kg + (size_t)(kbase + r) * DK);
        }
        e4[r] = (d < 0.f) ? __expf(d * 0.125f) : 0.f;
      }
      // attn bounce write: row q=l15, 16B-block b = kt*4+quad, swizzled position b^l15.
      f32x4 av = {e4[0] * zinv, e4[1] * zinv, e4[2] * zinv, e4[3] * zinv};
      *(f32x4*)(aw + l15 * 64 + ((kt * 4 + quad) ^ l15) * 4) = av;
      // es write: row q=l15, cols kt*16+quad*4 .. +3; block b = kt*2+(quad>>1), swz ^ (q&7)
      int bb = kt * 2 + (quad >> 1);
      short* ep = esw + l15 * 64 + ((bb ^ (l15 & 7)) * 8) + (quad & 1) * 4;
      *(short4*)ep = make_short4(f2bf(e4[0]), f2bf(e4[1]), f2bf(e4[2]), f2bf(e4[3]));
    }

    // ---- ALL loads before the stores (vmcnt FIFO: stores must be youngest) ----
    bf16x8 vv[4][2];                  // V fragments for this step (32 VGPR)
    #pragma unroll
    for (int dt = 0; dt < 4; ++dt)
      #pragma unroll
      for (int c = 0; c < 2; ++c)
        vv[dt][c] = *(const bf16x8*)(VW + (size_t)step * 4096 + (size_t)(dt * 16 + l15) * 64 +
                                     (((c * 4 + quad) ^ (l15 & 7)) * 8));
    if (step + 1 < NSTEP)
      QK_LOAD(kk, KW + (size_t)(step + 1) * 8192);   // K prefetch reuses kk (dead after MFMA)

    // attn store: 4 instrs, each 4 rows x 256B CONTIGUOUS (full 128B lines only).
    // lane l -> row r = 4i + (l>>4), col-block l&15 (read swizzled position (l&15)^r).
    #pragma unroll
    for (int i = 0; i < 4; ++i) {
      const int r = 4 * i + quad;
      f32x4 rv = *(const f32x4*)(aw + r * 64 + (l15 ^ r) * 4);
      __builtin_nontemporal_store(rv,
          (f32x4*)(attn_out + (size_t)(head * S_LEN + q0 + 16 * w + r) * S_LEN +
                   step * 64 + l15 * 4));
    }

    // PV: ctx^T += V^T * e^T (vv wait leaves the 16 K-prefetch + 4 stores outstanding).
    bf16x8 eb[2];
    #pragma unroll
    for (int c = 0; c < 2; ++c)
      eb[c] = *(const bf16x8*)(esw + l15 * 64 + (((c * 4 + quad) ^ (l15 & 7)) * 8));
    #pragma unroll
    for (int dt = 0; dt < 4; ++dt)
      #pragma unroll
      for (int c = 0; c < 2; ++c)
        ctxa[dt] = __builtin_amdgcn_mfma_f32_16x16x32_bf16(vv[dt][c], eb[c], ctxa[dt], 0, 0, 0);
  }

  // ctx store: thread holds ctx^T[d=dt*16+quad*4+r][q=qrow]; all 16 values share q -> zinv.
  #pragma unroll
  for (int dt = 0; dt < 4; ++dt) {
    float4 cv = {ctxa[dt][0] * zinv, ctxa[dt][1] * zinv, ctxa[dt][2] * zinv, ctxa[dt][3] * zinv};
    *(float4*)(ctx_out + (size_t)(head * S_LEN + qrow) * DK + dt * 16 + quad * 4) = cv;
  }
}

extern "C" void kernel_launch(void* const* d_in, const int* in_sizes, int n_in,
                              void* d_out, int out_size, void* d_ws, size_t ws_size,
                              hipStream_t stream) {
  const float* Q = (const float*)d_in[0];
  const float* K = (const float*)d_in[1];
  const float* V = (const float*)d_in[2];
  const int heads = in_sizes[0] / (S_LEN * DK);   // 24

  float* ctx = (float*)d_out;
  float* attn = (float*)d_out + (size_t)heads * S_LEN * DK;

  short* qw = (short*)d_ws;                                  // heads*2048*128 bf16
  short* kw = qw + (size_t)heads * S_LEN * 128;              // heads*128*16*128
  short* vw = kw + (size_t)heads * 128 * 16 * 128;           // heads*32*4096

  const int secblocks = heads * 64;                          // blocks per prep section
  prep_kernel<<<dim3(3 * secblocks), dim3(256), 0, stream>>>(Q, K, V, qw, kw, vw, secblocks);
  sdpa_mfma<<<dim3(NQB * heads), dim3(256), 0, stream>>>(Q, K, qw, kw, vw, ctx, attn);
}

// Round 7
// 579.169 us; speedup vs baseline: 1.1837x; 1.1837x over previous
//
#include <hip/hip_runtime.h>
#include <hip/hip_bf16.h>
#include <math.h>

// B=2,H=12 -> 24 heads, S=2048, D=64, fp32 in; out = ctx[24,2048,64] ++ attn[24,2048,2048].
//
// Round 9: q-split QK + LDS-shared V — cut per-CU vector-load traffic 4x.
//  Diagnosis: rounds 3-8 all bound by per-wave load redundancy: each wave loaded full
//  K+V slabs (24 KB/step); 12 waves/CU x same head = 288 KB/step/CU of L1 traffic
//  ~= 4.5k cy/step = the measured 325us. Fix:
//   - QK q-split: wave w owns k-quarter kt=step*4+w (4 KB/step), computes vs ALL 64 q
//     (qf[2][2][4] = 64 VGPR resident). Block K traffic = 1x slab.
//   - V staged once per block into LDS dbuf (reg->ds_write late, vmcnt-counted).
//   - e/attn cross-wave via swizzled LDS (es bf16 [64][64], att f32 [64][64]); sync by
//     raw s_barrier + lgkmcnt(0) ONLY -> no vmcnt(0) drain; loads issued before the
//     barrier, NT stores after -> QK wait = vmcnt(4), stores never block.
//   - 4-term QK split (adds mm plane, +8 MFMA/step): d error vs fmaf chain <= ~4e-4
//     -> DOT_EPS 1.5e-3; exact_dot fallback ~0.15/step/wave (was ~1/step).
//  PV per wave: q-tile w over all 64 k from shared es/Vs -> no ctx cross-wave reduce.

#define S_LEN 2048
#define DK    64
#define MQ    64
#define NSTEP 32
#define NQB   32
#define DOT_EPS 1.5e-3f

typedef __attribute__((ext_vector_type(8))) short bf16x8;
typedef __attribute__((ext_vector_type(4))) float f32x4;

__device__ inline short f2bf(float x) {
  __hip_bfloat16 b = __float2bfloat16(x);
  return *reinterpret_cast<short*>(&b);
}
__device__ inline float bf2f(short s) {
  __hip_bfloat16 b = *reinterpret_cast<__hip_bfloat16*>(&s);
  return __bfloat162float(b);
}

// exact round-1 score chain: sequential fmaf over d=0..63 (bit-identical to baseline)
__device__ float exact_dot(const float* __restrict__ Qr, const float* __restrict__ Kr) {
  float acc = 0.f;
  #pragma unroll
  for (int d4 = 0; d4 < 16; ++d4) {
    float4 a = ((const float4*)Qr)[d4];
    float4 b = ((const float4*)Kr)[d4];
    acc = fmaf(a.x, b.x, acc);
    acc = fmaf(a.y, b.y, acc);
    acc = fmaf(a.z, b.z, acc);
    acc = fmaf(a.w, b.w, acc);
  }
  return acc;
}

// ---------------- prep kernel: build bf16 planes in ws ----------------
// QW: per head [q][plane2][64]                       (plain)
// KW: per head [kt16:128][row16][plane2][blk8^ (row&7)][8]
// VW: per head [slab:32][d64][blk8 ^ (d&7)][8]       (V transposed: Vt[d][k])
__global__ __launch_bounds__(256) void prep_kernel(
    const float* __restrict__ Q, const float* __restrict__ K, const float* __restrict__ V,
    short* __restrict__ qw, short* __restrict__ kw, short* __restrict__ vw, int secblocks) {
  const int bid = blockIdx.x, tid = threadIdx.x;
  if (bid < secblocks) {               // ---- Q section ----
    int flat = bid * 256 + tid;        // (head, q, b) over heads*2048*8
    int head = flat >> 14;
    int rem = flat & 16383;
    int q = rem >> 3, b = rem & 7;
    const float* src = Q + (size_t)(head * S_LEN + q) * DK + b * 8;
    bf16x8 hv, mv;
    #pragma unroll
    for (int i = 0; i < 8; ++i) {
      float x = src[i];
      short h = f2bf(x);
      short m = f2bf(x - bf2f(h));
      hv[i] = h; mv[i] = m;
    }
    short* dst = qw + (size_t)(head * S_LEN + q) * 128;
    *(bf16x8*)(dst + 0 * 64 + b * 8) = hv;
    *(bf16x8*)(dst + 1 * 64 + b * 8) = mv;
  } else if (bid < 2 * secblocks) {    // ---- K section ----
    int flat = (bid - secblocks) * 256 + tid;   // (head, kt, row, b)
    int head = flat >> 14;
    int rem = flat & 16383;
    int kt = rem >> 7;
    int row = (rem >> 3) & 15, b = rem & 7;
    const float* src = K + (size_t)(head * S_LEN + kt * 16 + row) * DK + b * 8;
    bf16x8 hv, mv;
    #pragma unroll
    for (int i = 0; i < 8; ++i) {
      float x = src[i];
      short h = f2bf(x);
      short m = f2bf(x - bf2f(h));
      hv[i] = h; mv[i] = m;
    }
    int bs = b ^ (row & 7);
    short* dst = kw + ((size_t)(head * 128 + kt) * 16 + row) * 128;
    *(bf16x8*)(dst + 0 * 64 + bs * 8) = hv;
    *(bf16x8*)(dst + 1 * 64 + bs * 8) = mv;
  } else {                             // ---- V section (transpose) ----
    int wid = (bid - 2 * secblocks) * 4 + (tid >> 6);  // (head, slab, b) over heads*32*8
    int lane = tid & 63;               // = d
    int head = wid >> 8;
    int rem = wid & 255;
    int slab = rem >> 3, b = rem & 7;
    bf16x8 vv;
    #pragma unroll
    for (int j = 0; j < 8; ++j)
      vv[j] = f2bf(V[(size_t)(head * S_LEN + slab * 64 + b * 8 + j) * DK + lane]);
    int bs = b ^ (lane & 7);
    *(bf16x8*)(vw + ((size_t)(head * 32 + slab) * 64 + lane) * 64 + bs * 8) = vv;
  }
}

// ---------------- main kernel ----------------
__global__ __launch_bounds__(256, 3) void sdpa_mfma(
    const float* __restrict__ Q, const float* __restrict__ K,
    const short* __restrict__ qw, const short* __restrict__ kw, const short* __restrict__ vw,
    float* __restrict__ ctx_out, float* __restrict__ attn_out) {
  __shared__ float att[4096];     // 16KB: [q64][blk16 ^ (q&15)][4] f32 (overlay zred/zinv)
  __shared__ short es[4096];      // 8KB : [q64][blk8 ^ (q&7)][8] bf16
  __shared__ short Vs[2][4096];   // 16KB: dbuf, verbatim vw slab copy (8KB each)

  // XCD-aware decode: all 32 q-blocks of a head on one XCD (L2-resident kw/vw).
  const int b = blockIdx.x;
  const int inner = b >> 3;
  const int qb = inner & (NQB - 1);
  const int head = (b & 7) + 8 * (inner >> 5);
  const int q0 = qb * MQ;
  const int tid = threadIdx.x;
  const int w = tid >> 6;
  const int lane = tid & 63;
  const int l15 = lane & 15;
  const int quad = lane >> 4;

  const short* QW = qw + (size_t)head * (S_LEN * 128);
  const short* KW = kw + (size_t)head * (128 * 16 * 128);
  const short* VW = vw + (size_t)head * (32 * 4096);
  const float* Qg = Q + (size_t)head * S_LEN * DK;
  const float* Kg = K + (size_t)head * S_LEN * DK;

  const f32x4 zf = {0.f, 0.f, 0.f, 0.f};

  // Q B-fragments for ALL FOUR q-tiles (64 VGPR, resident). B[k=d][n=q]: n=l15 ->
  // q = qt*16+l15; k = c*32 + quad*8 + j.
  bf16x8 qf[2][2][4];   // [plane][chunk][qt]
  #pragma unroll
  for (int p = 0; p < 2; ++p)
    #pragma unroll
    for (int c = 0; c < 2; ++c)
      #pragma unroll
      for (int qt = 0; qt < 4; ++qt)
        qf[p][c][qt] = *(const bf16x8*)(QW + (size_t)(q0 + qt * 16 + l15) * 128 + p * 64 + (c * 4 + quad) * 8);

  // K-fragment load for ONE 16-k tile (4 loads, 16 VGPR)
  #define KK_LOAD(dst, kt)                                                                     \
    {                                                                                          \
      const short* kb_ = KW + ((size_t)(kt) * 16 + l15) * 128;                                 \
      _Pragma("unroll")                                                                        \
      for (int p = 0; p < 2; ++p)                                                              \
        _Pragma("unroll")                                                                      \
        for (int c = 0; c < 2; ++c)                                                            \
          dst[p][c] = *(const bf16x8*)(kb_ + p * 64 + (((c * 4 + quad) ^ (l15 & 7)) * 8));     \
    }

  // 4-term split QK vs all 4 q-tiles: 32 MFMA. C[m=k][n=q]: col=l15=q, row=quad*4+r.
  #define QK_MFMA4(acc, kkv)                                                                   \
    {                                                                                          \
      _Pragma("unroll")                                                                        \
      for (int qt = 0; qt < 4; ++qt)                                                           \
        _Pragma("unroll")                                                                      \
        for (int c = 0; c < 2; ++c) {                                                          \
          acc[qt] = __builtin_amdgcn_mfma_f32_16x16x32_bf16(kkv[0][c], qf[0][c][qt], acc[qt], 0, 0, 0); \
          acc[qt] = __builtin_amdgcn_mfma_f32_16x16x32_bf16(kkv[1][c], qf[0][c][qt], acc[qt], 0, 0, 0); \
          acc[qt] = __builtin_amdgcn_mfma_f32_16x16x32_bf16(kkv[0][c], qf[1][c][qt], acc[qt], 0, 0, 0); \
          acc[qt] = __builtin_amdgcn_mfma_f32_16x16x32_bf16(kkv[1][c], qf[1][c][qt], acc[qt], 0, 0, 0); \
        }                                                                                      \
    }

  bf16x8 kA[2][2], kB[2][2];

  // ================= pass A: Z (wave w sweeps its k-quarter; no barriers) ================
  float zp[4] = {0.f, 0.f, 0.f, 0.f};
  KK_LOAD(kA, w);                       // tile for step 0
  for (int t = 0; t < NSTEP; t += 2) {
    KK_LOAD(kB, (t + 1) * 4 + w);
    {
      f32x4 acc[4] = {zf, zf, zf, zf};
      QK_MFMA4(acc, kA);
      #pragma unroll
      for (int qt = 0; qt < 4; ++qt)
        #pragma unroll
        for (int r = 0; r < 4; ++r) {
          float d = acc[qt][r];
          zp[qt] += (d < 0.f) ? __expf(d * 0.125f) : 0.f;
        }
    }
    KK_LOAD(kA, (((t + 2) & 31)) * 4 + w);
    {
      f32x4 acc[4] = {zf, zf, zf, zf};
      QK_MFMA4(acc, kB);
      #pragma unroll
      for (int qt = 0; qt < 4; ++qt)
        #pragma unroll
        for (int r = 0; r < 4; ++r) {
          float d = acc[qt][r];
          zp[qt] += (d < 0.f) ? __expf(d * 0.125f) : 0.f;
        }
    }
  }

  // Z reduce: quads (k within tile) via shfl; k-quarters (waves) via LDS.
  float* zredp = att;                   // [4][64] overlay
  float* zinvp = att + 256;
  #pragma unroll
  for (int qt = 0; qt < 4; ++qt) {
    float v = zp[qt];
    v += __shfl_xor(v, 16);
    v += __shfl_xor(v, 32);
    if (lane < 16) zredp[w * 64 + qt * 16 + l15] = v;
  }
  __syncthreads();
  if (tid < 64)
    zinvp[tid] = 1.f / (zredp[tid] + zredp[64 + tid] + zredp[128 + tid] + zredp[192 + tid] + 1e-8f);
  __syncthreads();
  float ziq[4];
  #pragma unroll
  for (int qt = 0; qt < 4; ++qt) ziq[qt] = zinvp[qt * 16 + l15];
  const float zctx = zinvp[16 * w + l15];
  __syncthreads();                      // zinv consumed; att free for pass B

  // ================= pass B =================
  f32x4 ctxa[4] = {zf, zf, zf, zf};     // ctx^T q-tile w: [dt]; row d=dt*16+quad*4+r, col q=16w+l15
  bf16x8 vr0, vr1;

  // prologue: stage Vs[0] <- slab 0 (reg->lds), load kA <- tile w (step 0)
  {
    const short* gs = VW + w * 1024;
    vr0 = *(const bf16x8*)(gs + lane * 8);
    vr1 = *(const bf16x8*)(gs + 512 + lane * 8);
  }
  KK_LOAD(kA, w);
  {
    short* ls = &Vs[0][w * 1024];
    *(bf16x8*)(ls + lane * 8) = vr0;
    *(bf16x8*)(ls + 512 + lane * 8) = vr1;
  }
  asm volatile("s_waitcnt lgkmcnt(0)" ::: "memory");
  __builtin_amdgcn_s_barrier();

  // Per half-step s: QK(quarter w vs 64q) -> e4 -> es/att writes -> issue next V+K loads
  // -> lgkm+barrier -> full-line NT attn stores -> PV(q-tile w, all 64k) -> Vs write ->
  // lgkm+barrier. Stores are always the youngest VM ops -> QK wait = vmcnt(4).
  #define PASSB_HALF(s, VCUR, VNXT, KKU, KKL)                                                  \
  {                                                                                            \
    f32x4 acc[4] = {zf, zf, zf, zf};                                                           \
    QK_MFMA4(acc, KKU);                                                                        \
    _Pragma("unroll")                                                                          \
    for (int qt = 0; qt < 4; ++qt) {                                                           \
      const int qe = qt * 16 + l15;                                                            \
      const int kbase = (s) * 64 + w * 16 + quad * 4;                                          \
      float e4[4];                                                                             \
      _Pragma("unroll")                                                                        \
      for (int r = 0; r < 4; ++r) {                                                            \
        float d = acc[qt][r];                                                                  \
        if (fabsf(d) < DOT_EPS)                                                                \
          d = exact_dot(Qg + (size_t)(q0 + qe) * DK, Kg + (size_t)(kbase + r) * DK);           \
        e4[r] = (d < 0.f) ? __expf(d * 0.125f) : 0.f;                                          \
      }                                                                                        \
      f32x4 av = {e4[0] * ziq[qt], e4[1] * ziq[qt], e4[2] * ziq[qt], e4[3] * ziq[qt]};         \
      ((f32x4*)att)[qe * 16 + ((w * 4 + quad) ^ l15)] = av;                                    \
      *(short4*)&es[qe * 64 + (((w * 2 + (quad >> 1)) ^ (l15 & 7)) * 8) + (quad & 1) * 4] =    \
          make_short4(f2bf(e4[0]), f2bf(e4[1]), f2bf(e4[2]), f2bf(e4[3]));                     \
    }                                                                                          \
    {                                                                                          \
      const short* gs = VW + (size_t)(((s) + 1) & 31) * 4096 + w * 1024;                       \
      vr0 = *(const bf16x8*)(gs + lane * 8);                                                   \
      vr1 = *(const bf16x8*)(gs + 512 + lane * 8);                                             \
    }                                                                                          \
    KK_LOAD(KKL, ((((s) + 1) & 31)) * 4 + w);                                                  \
    asm volatile("s_waitcnt lgkmcnt(0)" ::: "memory");                                         \
    __builtin_amdgcn_s_barrier();                                                              \
    _Pragma("unroll")                                                                          \
    for (int i = 0; i < 4; ++i) {                                                              \
      const int r = 4 * i + quad;                                                              \
      f32x4 rv = ((const f32x4*)att)[(16 * w + r) * 16 + (l15 ^ r)];                           \
      __builtin_nontemporal_store(rv, (f32x4*)(attn_out +                                      \
          (size_t)(head * S_LEN + q0 + 16 * w + r) * S_LEN + (s) * 64 + l15 * 4));             \
    }                                                                                          \
    {                                                                                          \
      bf16x8 ea[2];                                                                            \
      _Pragma("unroll")                                                                        \
      for (int c = 0; c < 2; ++c)                                                              \
        ea[c] = *(const bf16x8*)&es[(16 * w + l15) * 64 + (((c * 4 + quad) ^ (l15 & 7)) * 8)]; \
      _Pragma("unroll")                                                                        \
      for (int dt = 0; dt < 4; ++dt)                                                           \
        _Pragma("unroll")                                                                      \
        for (int c = 0; c < 2; ++c) {                                                          \
          bf16x8 va = *(const bf16x8*)&VCUR[(dt * 16 + l15) * 64 + (((c * 4 + quad) ^ (l15 & 7)) * 8)]; \
          ctxa[dt] = __builtin_amdgcn_mfma_f32_16x16x32_bf16(va, ea[c], ctxa[dt], 0, 0, 0);    \
        }                                                                                      \
    }                                                                                          \
    {                                                                                          \
      short* ls = &VNXT[w * 1024];                                                             \
      *(bf16x8*)(ls + lane * 8) = vr0;                                                         \
      *(bf16x8*)(ls + 512 + lane * 8) = vr1;                                                   \
    }                                                                                          \
    asm volatile("s_waitcnt lgkmcnt(0)" ::: "memory");                                         \
    __builtin_amdgcn_s_barrier();                                                              \
  }

  for (int t = 0; t < NSTEP; t += 2) {
    PASSB_HALF(t,     Vs[0], Vs[1], kA, kB)
    PASSB_HALF(t + 1, Vs[1], Vs[0], kB, kA)
  }

  // ctx store: thread holds ctx^T[d=dt*16+quad*4+r][q=16w+l15]; zctx = zinv of its q.
  #pragma unroll
  for (int dt = 0; dt < 4; ++dt) {
    float4 cv = {ctxa[dt][0] * zctx, ctxa[dt][1] * zctx, ctxa[dt][2] * zctx, ctxa[dt][3] * zctx};
    *(float4*)(ctx_out + (size_t)(head * S_LEN + q0 + 16 * w + l15) * DK + dt * 16 + quad * 4) = cv;
  }
}

extern "C" void kernel_launch(void* const* d_in, const int* in_sizes, int n_in,
                              void* d_out, int out_size, void* d_ws, size_t ws_size,
                              hipStream_t stream) {
  const float* Q = (const float*)d_in[0];
  const float* K = (const float*)d_in[1];
  const float* V = (const float*)d_in[2];
  const int heads = in_sizes[0] / (S_LEN * DK);   // 24

  float* ctx = (float*)d_out;
  float* attn = (float*)d_out + (size_t)heads * S_LEN * DK;

  short* qw = (short*)d_ws;                                  // heads*2048*128 bf16
  short* kw = qw + (size_t)heads * S_LEN * 128;              // heads*128*16*128
  short* vw = kw + (size_t)heads * 128 * 16 * 128;           // heads*32*4096

  const int secblocks = heads * 64;                          // blocks per prep section
  prep_kernel<<<dim3(3 * secblocks), dim3(256), 0, stream>>>(Q, K, V, qw, kw, vw, secblocks);
  sdpa_mfma<<<dim3(NQB * heads), dim3(256), 0, stream>>>(Q, K, qw, kw, vw, ctx, attn);
}